// Round 15
// baseline (309.641 us; speedup 1.0000x reference)
//
#include <hip/hip_runtime.h>
#include <hip/hip_bf16.h>

typedef __bf16 bf16;
typedef __attribute__((ext_vector_type(8))) __bf16 bf16x8;
typedef __attribute__((ext_vector_type(4))) __bf16 bf16x4;
typedef __attribute__((ext_vector_type(4))) float f32x4;
typedef __attribute__((ext_vector_type(4))) unsigned int u32x4;

#define LN_EPS 1e-5f

__device__ __forceinline__ void gload16(const void* g, void* l) {
  __builtin_amdgcn_global_load_lds(
      (__attribute__((address_space(1))) void*)g,
      (__attribute__((address_space(3))) void*)l, 16, 0, 0);
}

__device__ __forceinline__ unsigned pk2(float a, float b) {
  unsigned ua = __builtin_bit_cast(unsigned short, (bf16)a);
  unsigned ub = __builtin_bit_cast(unsigned short, (bf16)b);
  return ua | (ub << 16);
}

__device__ __forceinline__ float fexp2(float x) {
  float r;
  asm("v_exp_f32 %0, %1" : "=v"(r) : "v"(x));
  return r;
}

// ---------------- t_in + all prep merged into ONE launch ----------------
// bid ranges: [0,3136) t_in | then prep: +[0,2) bn | +[2,258) qkvo
//   +[258,386) w1 | +[386,514) w2 | +[514,642) cvt2 | +[642,5250) wprep
struct PrepArgs {
  const float *cl_b, *bnl_g, *bnl_b, *bnl_m, *bnl_v;
  const float *ci_b, *bni_g, *bni_b, *bni_m, *bni_v;
  float *scale_l, *shift_l, *scale_i, *shift_i, *zp;
  const float *qw, *kw, *vw, *ow;
  bf16 *qwT, *kwT, *vwT, *owT;
  const float *w1, *w2;
  bf16 *w1t, *w2t;
  const float *op_w, *sp_w;
  bf16 *opwB, *spwB;
  const float *cl_w, *ci_w;
  bf16 *clwT, *ciwT;
  const float *lid, *img;
  bf16 *lidT, *imgT;
};

__global__ __launch_bounds__(256) void tin_prep_k(PrepArgs a) {
  __shared__ unsigned smem[128 * 68];  // t_in tile; aliased as f32[32][33] for prep
  const int bid0 = blockIdx.x;
  const int t = threadIdx.x;
  if (bid0 < 3136) {  // ---- t_in v5: NCHW f32 -> NHWC bf16 ----
    int z = bid0 & 3;
    int rest = bid0 >> 2;
    int b = z & 1;
    const float* in = (z < 2) ? a.lid : a.img;
    bf16* out = (z < 2) ? a.lidT : a.imgT;
    int c0 = (rest & 1) * 128;
    long p0 = (long)(rest >> 1) * 128;
    const float* ib = in + (long)b * 256 * 50176;
    bf16* ob = out + (long)b * 50176 * 256;
    int q = t & 31;
    int cp = t >> 5;
#pragma unroll
    for (int pp = 0; pp < 8; ++pp) {
      int chl = pp * 16 + cp * 2;
      const float* s = ib + (long)(c0 + chl) * 50176 + p0 + q * 4;
      float4 av = *(const float4*)s;
      float4 bv = *(const float4*)(s + 50176);
      unsigned wv[4] = {pk2(av.x, bv.x), pk2(av.y, bv.y), pk2(av.z, bv.z),
                        pk2(av.w, bv.w)};
      int c = pp * 8 + cp;
#pragma unroll
      for (int j = 0; j < 4; ++j)
        smem[(q * 4 + j) * 68 + c] = wv[j];
    }
    __syncthreads();
    int c8 = t & 15;
#pragma unroll
    for (int pp = 0; pp < 8; ++pp) {
      int p = pp * 16 + (t >> 4);
      u32x4 vv = *(const u32x4*)&smem[p * 68 + c8 * 4];
      *(u32x4*)(ob + (p0 + p) * 256 + c0 + c8 * 8) = vv;
    }
    return;
  }
  const int bid = bid0 - 3136;
  float(*tile)[33] = (float(*)[33])smem;
  if (bid < 2) {  // bn_prep + zero page
    bool z = bid != 0;
    const float* cb = z ? a.ci_b : a.cl_b;
    const float* g = z ? a.bni_g : a.bnl_g;
    const float* bb = z ? a.bni_b : a.bnl_b;
    const float* m = z ? a.bni_m : a.bnl_m;
    const float* v = z ? a.bni_v : a.bnl_v;
    float* sc = z ? a.scale_i : a.scale_l;
    float* sh = z ? a.shift_i : a.shift_l;
    float s = g[t] * rsqrtf(v[t] + LN_EPS);
    sc[t] = s;
    sh[t] = (cb[t] - m[t]) * s + bb[t];
    if (bid == 0) a.zp[t] = 0.f;
  } else if (bid < 514) {  // transpose-convert family
    const float* in;
    bf16* out;
    int c0, r0, R, Cc;
    if (bid < 258) {
      int idx = bid - 2;
      int z = idx >> 6, rem = idx & 63;
      in = z == 0 ? a.qw : z == 1 ? a.kw : z == 2 ? a.vw : a.ow;
      out = z == 0 ? a.qwT : z == 1 ? a.kwT : z == 2 ? a.vwT : a.owT;
      c0 = (rem & 7) * 32;
      r0 = (rem >> 3) * 32;
      R = 256; Cc = 256;
    } else if (bid < 386) {
      int idx = bid - 258;
      in = a.w1; out = a.w1t;
      c0 = (idx & 15) * 32;
      r0 = (idx >> 4) * 32;
      R = 256; Cc = 512;
    } else {
      int idx = bid - 386;
      in = a.w2; out = a.w2t;
      c0 = (idx & 7) * 32;
      r0 = (idx >> 3) * 32;
      R = 512; Cc = 256;
    }
    int tx = t & 31, ty = t >> 5;
    for (int yy = ty; yy < 32; yy += 8)
      tile[yy][tx] = in[(long)(r0 + yy) * Cc + c0 + tx];
    __syncthreads();
    for (int yy = ty; yy < 32; yy += 8)
      out[(long)(c0 + yy) * R + r0 + tx] = (bf16)tile[tx][yy];
  } else if (bid < 642) {  // cvt2: op_w / sp_w flat convert
    int idx = bid - 514;
    int bx = idx & 63;
    const float* in = (idx >> 6) ? a.sp_w : a.op_w;
    bf16* out = (idx >> 6) ? a.spwB : a.opwB;
    int i = (bx * 256 + t) * 4;
    float4 v = *(const float4*)(in + i);
    bf16x4 o = {(bf16)v.x, (bf16)v.y, (bf16)v.z, (bf16)v.w};
    *(bf16x4*)(out + i) = o;
  } else {  // wprep: conv weights OIHW -> [co][k9*256+ci]
    int idx = bid - 642;
    int bx = idx % 2304;
    const float* w = (idx / 2304) ? a.ci_w : a.cl_w;
    bf16* o = (idx / 2304) ? a.ciwT : a.clwT;
    int gi = bx * 256 + t;
    int co = gi / 2304, r = gi - co * 2304;
    int k9 = r >> 8, ci = r & 255;
    o[gi] = (bf16)w[(co * 256 + ci) * 9 + k9];
  }
}

__global__ void ln_k(const float* __restrict__ in, const float* __restrict__ g,
                     const float* __restrict__ bb, float* __restrict__ outf,
                     bf16* __restrict__ outb) {
  int w = threadIdx.x >> 6, l = threadIdx.x & 63;
  long row = (long)blockIdx.x * 4 + w;
  float4 v = *(const float4*)(in + row * 256 + l * 4);
  float s = v.x + v.y + v.z + v.w;
  for (int m = 1; m < 64; m <<= 1) s += __shfl_xor(s, m);
  float mu = s * (1.0f / 256.0f);
  float dx = v.x - mu, dy = v.y - mu, dz = v.z - mu, dw = v.w - mu;
  float q = dx * dx + dy * dy + dz * dz + dw * dw;
  for (int m = 1; m < 64; m <<= 1) q += __shfl_xor(q, m);
  float rstd = rsqrtf(q * (1.0f / 256.0f) + LN_EPS);
  int c = l * 4;
  float y0 = dx * rstd * g[c] + bb[c];
  float y1 = dy * rstd * g[c + 1] + bb[c + 1];
  float y2 = dz * rstd * g[c + 2] + bb[c + 2];
  float y3 = dw * rstd * g[c + 3] + bb[c + 3];
  if (outf) {
    float4 o = {y0, y1, y2, y3};
    *(float4*)(outf + row * 256 + c) = o;
  }
  bf16x4 ob = {(bf16)y0, (bf16)y1, (bf16)y2, (bf16)y3};
  *(bf16x4*)(outb + row * 256 + c) = ob;
}

// ---------------- conv GEMM with implicit im2col (NHWC input) ----------------
struct ConvJob {
  const bf16* inT;
  const bf16* wT;
  const float* scale;
  const float* shift;
  bf16* out;
};

__global__ __launch_bounds__(256) void convgemm_k(ConvJob j0, ConvJob j1,
                                                  const bf16* zp) {
  const ConvJob jb = blockIdx.z ? j1 : j0;
  __shared__ bf16 lA[64 * 64];
  __shared__ bf16 lB[64 * 64];
  const int tid = threadIdx.x;
  const int w = tid >> 6, l = tid & 63;
  const int l15 = l & 15;
  const int m0 = blockIdx.x * 64;
  const int n0 = blockIdx.y * 64;
  const int mw = (w >> 1) * 32, nw = (w & 1) * 32;
  f32x4 acc[2][2] = {};
  const int srow = w * 8 + (l >> 3);
  const int kc8 = (l & 7) * 8;
  long rb[2];
  int voy[2], vox[2];
#pragma unroll
  for (int p = 0; p < 2; ++p) {
    int m = m0 + srow + p * 32;
    int b = m / 3136;
    int mm = m - b * 3136;
    int oy = mm / 56, ox = mm - oy * 56;
    rb[p] = ((long)b * 50176 + (long)(4 * oy - 1) * 224 + (4 * ox - 1)) * 256 + kc8;
    voy[p] = oy;
    vox[p] = ox;
  }
  const bf16* Bb = jb.wT + (long)(n0 + srow) * 2304 + kc8;
  bf16* lAp = &lA[srow * 64 + kc8];
  bf16* lBp = &lB[srow * 64 + kc8];
  const bf16* zsrc = zp + kc8;
#pragma unroll
  for (int st = 0; st < 36; ++st) {
    const int k9 = st >> 2, ci0 = (st & 3) * 64;
    const int ky = k9 / 3, kx = k9 - 3 * ky;
    const long koff = (long)(ky * 224 + kx) * 256 + ci0;
#pragma unroll
    for (int p = 0; p < 2; ++p) {
      bool ok = (voy[p] > 0 || ky > 0) && (vox[p] > 0 || kx > 0);
      const bf16* src = ok ? jb.inT + rb[p] + koff : zsrc;
      gload16(src, lAp + p * 32 * 64);
    }
    gload16(Bb + st * 64, lBp);
    gload16(Bb + 32 * 2304 + st * 64, lBp + 32 * 64);
    __syncthreads();
    const int kq = (l >> 4) * 8;
#pragma unroll
    for (int kk = 0; kk < 64; kk += 32) {
      bf16x8 af[2], bfv[2];
#pragma unroll
      for (int i = 0; i < 2; ++i)
        af[i] = *(const bf16x8*)&lA[(mw + i * 16 + l15) * 64 + kk + kq];
#pragma unroll
      for (int j = 0; j < 2; ++j)
        bfv[j] = *(const bf16x8*)&lB[(nw + j * 16 + l15) * 64 + kk + kq];
#pragma unroll
      for (int i = 0; i < 2; ++i)
#pragma unroll
        for (int j = 0; j < 2; ++j)
          acc[i][j] = __builtin_amdgcn_mfma_f32_16x16x32_bf16(af[i], bfv[j],
                                                              acc[i][j], 0, 0, 0);
    }
    __syncthreads();
  }
#pragma unroll
  for (int i = 0; i < 2; ++i)
#pragma unroll
    for (int j = 0; j < 2; ++j)
#pragma unroll
      for (int r = 0; r < 4; ++r) {
        const long row = m0 + mw + i * 16 + (l >> 4) * 4 + r;
        const long col = n0 + nw + j * 16 + l15;
        float v = fmaxf(acc[i][j][r] * jb.scale[col] + jb.shift[col], 0.f);
        jb.out[row * 256 + col] = (bf16)v;
      }
}

// ---------------- generic GEMM (templated BM/BN) ----------------

struct EpiParams {
  float* out0;
  bf16* out1;
  const float* v0;
  const float* res;
  const bf16* resb;
  int ldc;
  float mul;
};

struct GemmJob {
  const bf16* A;
  const bf16* Bt;
  EpiParams ep;
};

struct GemmJobs3 {
  GemmJob j[3];
};

enum { EPI_QKV = 0, EPI_BIAS_RELU_BF16 = 1, EPI_BIAS_ADD = 2,
       EPI_BIAS_ADDB = 3, EPI_ROWB_F32 = 4, EPI_FINAL2 = 5, EPI_QKV_VT = 6 };

template <int EPI, int BM, int BN>
__global__ __launch_bounds__(256) void gemm_bt(GemmJobs3 jobs, int K) {
  const GemmJob jb = jobs.j[blockIdx.z];
  const bf16* __restrict__ A = jb.A;
  const bf16* __restrict__ Bt = jb.Bt;
  const EpiParams ep = jb.ep;
  constexpr int MI = (BM == 128 && BN == 128) ? 4 : 2;
  constexpr int NJ = (BN == 128) ? 4 : 2;
  __shared__ bf16 lA[BM * 64];
  __shared__ bf16 lB[BN * 64];
  const int tid = threadIdx.x;
  const int w = tid >> 6, l = tid & 63;
  const int l15 = l & 15;
  const long m0 = (long)blockIdx.x * BM;
  const long n0 = (long)blockIdx.y * BN;
  const int mw = (BM == 128) ? ((BN == 128) ? (w >> 1) * 64 : w * 32)
                             : (w >> 1) * 32;
  const int nw = (BN == 128) ? (w & 1) * 64 : ((BM == 128) ? 0 : (w & 1) * 32);
  f32x4 acc[MI][NJ] = {};
  const int srow = w * 8 + (l >> 3);
  const int kc8 = (l & 7) * 8;
  const bf16* Ab = A + (m0 + srow) * (long)K + kc8;
  const bf16* Bb = Bt + (n0 + srow) * (long)K + kc8;
  bf16* lAp = &lA[srow * 64 + kc8];
  bf16* lBp = &lB[srow * 64 + kc8];
  for (int k0 = 0; k0 < K; k0 += 64) {
#pragma unroll
    for (int p = 0; p < BM / 32; ++p)
      gload16(Ab + (long)p * 32 * K + k0, lAp + p * 32 * 64);
#pragma unroll
    for (int p = 0; p < BN / 32; ++p)
      gload16(Bb + (long)p * 32 * K + k0, lBp + p * 32 * 64);
    __syncthreads();
    const int kq = (l >> 4) * 8;
#pragma unroll
    for (int kk = 0; kk < 64; kk += 32) {
      bf16x8 af[MI], bfv[NJ];
#pragma unroll
      for (int i = 0; i < MI; ++i)
        af[i] = *(const bf16x8*)&lA[(mw + i * 16 + l15) * 64 + kk + kq];
#pragma unroll
      for (int j = 0; j < NJ; ++j)
        bfv[j] = *(const bf16x8*)&lB[(nw + j * 16 + l15) * 64 + kk + kq];
#pragma unroll
      for (int i = 0; i < MI; ++i)
#pragma unroll
        for (int j = 0; j < NJ; ++j)
          acc[i][j] = __builtin_amdgcn_mfma_f32_16x16x32_bf16(af[i], bfv[j],
                                                              acc[i][j], 0, 0, 0);
    }
    __syncthreads();
  }
  const int ldc = ep.ldc;
#pragma unroll
  for (int i = 0; i < MI; ++i)
#pragma unroll
    for (int j = 0; j < NJ; ++j) {
      if constexpr (EPI == EPI_QKV_VT) {
        const long row0 = m0 + mw + i * 16 + (l >> 4) * 4;
        const int b = (int)(row0 / 3136);
        const int n = (int)(row0 - (long)b * 3136);
        const long col = n0 + nw + j * 16 + l15;
        bf16x4 ov;
#pragma unroll
        for (int r = 0; r < 4; ++r)
          ov[r] = (bf16)(acc[i][j][r] + ep.v0[col]);
        *(bf16x4*)(ep.out1 + ((long)b * 256 + col) * 3136 + n) = ov;
      } else if constexpr (EPI == EPI_FINAL2) {
        const long col = n0 + nw + j * 16 + l15;
        int colp = (int)col;
        int y = colp / 224, x = colp - y * 224;
        int ry = y & 3, rx = x & 3;
        int y0 = (y >> 2) - 1 + (ry >> 1);
        int x0 = (x >> 2) - 1 + (rx >> 1);
        float wy = (ry == 0) ? 0.625f : (ry == 1) ? 0.875f : (ry == 2) ? 0.125f : 0.375f;
        float wx = (rx == 0) ? 0.625f : (rx == 1) ? 0.875f : (rx == 2) ? 0.125f : 0.375f;
        int y0c = y0 > 0 ? y0 : 0, y1c = (y0 + 1) < 55 ? (y0 + 1) : 55;
        int x0c = x0 > 0 ? x0 : 0, x1c = (x0 + 1) < 55 ? (x0 + 1) : 55;
        const int o00 = y0c * 56 + x0c, o01 = y0c * 56 + x1c;
        const int o10 = y1c * 56 + x0c, o11 = y1c * 56 + x1c;
        const float w11 = wy * wx, w10 = wy * (1.f - wx);
        const float w01 = (1.f - wy) * wx, w00 = (1.f - wy) * (1.f - wx);
#pragma unroll
        for (int r = 0; r < 4; ++r) {
          const long row = m0 + mw + i * 16 + (l >> 4) * 4 + r;
          const float* ocr = ep.res + row * 3136;
          float up = w00 * ocr[o00] + w01 * ocr[o01] + w10 * ocr[o10] +
                     w11 * ocr[o11];
          ep.out0[row * ldc + col] = acc[i][j][r] + ep.v0[row] + up;
        }
      } else {
#pragma unroll
        for (int r = 0; r < 4; ++r) {
          const long row = m0 + mw + i * 16 + (l >> 4) * 4 + r;
          const long col = n0 + nw + j * 16 + l15;
          float v = acc[i][j][r];
          if constexpr (EPI == EPI_QKV) {
            ep.out1[row * ldc + col] = (bf16)((v + ep.v0[col]) * ep.mul);
          } else if constexpr (EPI == EPI_BIAS_RELU_BF16) {
            ep.out1[row * ldc + col] = (bf16)fmaxf(v + ep.v0[col], 0.f);
          } else if constexpr (EPI == EPI_BIAS_ADD) {
            ep.out0[row * ldc + col] = v + ep.v0[col] + ep.res[row * ldc + col];
          } else if constexpr (EPI == EPI_BIAS_ADDB) {
            ep.out0[row * ldc + col] =
                v + ep.v0[col] + (float)ep.resb[row * ldc + col];
          } else if constexpr (EPI == EPI_ROWB_F32) {
            ep.out0[row * ldc + col] = v + ep.v0[row];
          }
        }
      }
    }
}

// ---------------- flash attention v5 (unchanged) ----------------
__global__ __launch_bounds__(256) void flash_k(const bf16* __restrict__ Qg,
                                               const bf16* __restrict__ Kg,
                                               const bf16* __restrict__ Vt,
                                               bf16* __restrict__ ctx) {
  const int w = threadIdx.x >> 6, l = threadIdx.x & 63;
  const int fid = blockIdx.x;
  const int grp = (fid & 7) * 2 + ((fid >> 3) / 49);
  const int qt = (fid >> 3) % 49;
  const int b = grp >> 3, h = grp & 7;
  const int N = 3136;
  const int l15 = l & 15, g = l >> 4;
  const int q0 = (qt * 4 + w) * 16;
  const int kperm = 8 * (l15 >> 2) + (l15 & 3);
  __shared__ bf16 lds[2][4][512];

  bf16x8 qf = *(const bf16x8*)(Qg + ((long)(b * N + q0 + l15)) * 256 + h * 32 + g * 8);
  const bf16* Kb_ = Kg + ((long)b * N) * 256 + h * 32;
  const bf16* Vb_ = Vt + ((long)(b * 256 + h * 32)) * 3136;
  const long kOffA = (long)kperm * 256 + g * 8;
  const long kOffB = (long)(kperm + 4) * 256 + g * 8;
  const long vOff0 = (long)l15 * 3136 + g * 8;
  const long vOff1 = (long)(16 + l15) * 3136 + g * 8;

  f32x4 o0 = {}, o1 = {};
  float ls = 0.f;

  auto stage = [&](int buf, int kt) {
    const bf16* kp = Kb_ + (long)kt * 32 * 256;
    const bf16* vp = Vb_ + kt * 32;
    if (w == 0)
      gload16(kp + kOffA, &lds[buf][0][l * 8]);
    else if (w == 1)
      gload16(kp + kOffB, &lds[buf][1][l * 8]);
    else if (w == 2)
      gload16(vp + vOff0, &lds[buf][2][l * 8]);
    else
      gload16(vp + vOff1, &lds[buf][3][l * 8]);
  };

  stage(0, 0);
  __syncthreads();
  int cur = 0;
  for (int kt = 0; kt < 98; ++kt) {
    if (kt < 97) stage(cur ^ 1, kt + 1);
    bf16x8 kf0 = *(const bf16x8*)&lds[cur][0][l * 8];
    bf16x8 kf1 = *(const bf16x8*)&lds[cur][1][l * 8];
    bf16x8 vf0 = *(const bf16x8*)&lds[cur][2][l * 8];
    bf16x8 vf1 = *(const bf16x8*)&lds[cur][3][l * 8];
    f32x4 z = {};
    f32x4 s0 = __builtin_amdgcn_mfma_f32_16x16x32_bf16(kf0, qf, z, 0, 0, 0);
    f32x4 s1 = __builtin_amdgcn_mfma_f32_16x16x32_bf16(kf1, qf, z, 0, 0, 0);
    float p0 = fexp2(s0[0]), p1 = fexp2(s0[1]), p2 = fexp2(s0[2]), p3 = fexp2(s0[3]);
    float p4 = fexp2(s1[0]), p5 = fexp2(s1[1]), p6 = fexp2(s1[2]), p7 = fexp2(s1[3]);
    ls += ((p0 + p1) + (p2 + p3)) + ((p4 + p5) + (p6 + p7));
    u32x4 fp;
    fp[0] = pk2(p0, p1);
    fp[1] = pk2(p2, p3);
    fp[2] = pk2(p4, p5);
    fp[3] = pk2(p6, p7);
    bf16x8 pf = __builtin_bit_cast(bf16x8, fp);
    o0 = __builtin_amdgcn_mfma_f32_16x16x32_bf16(vf0, pf, o0, 0, 0, 0);
    o1 = __builtin_amdgcn_mfma_f32_16x16x32_bf16(vf1, pf, o1, 0, 0, 0);
    __syncthreads();
    cur ^= 1;
  }
  ls += __shfl_xor(ls, 16);
  ls += __shfl_xor(ls, 32);
  float inv = 1.0f / ls;
  long base = ((long)(b * N + q0 + l15)) * 256 + h * 32;
  bf16x4 ov0 = {(bf16)(o0[0] * inv), (bf16)(o0[1] * inv),
                (bf16)(o0[2] * inv), (bf16)(o0[3] * inv)};
  bf16x4 ov1 = {(bf16)(o1[0] * inv), (bf16)(o1[1] * inv),
                (bf16)(o1[2] * inv), (bf16)(o1[3] * inv)};
  *(bf16x4*)(ctx + base + g * 4) = ov0;
  *(bf16x4*)(ctx + base + 16 + g * 4) = ov1;
}

// ---------------- launch ----------------

extern "C" void kernel_launch(void* const* d_in, const int* in_sizes, int n_in,
                              void* d_out, int out_size, void* d_ws, size_t ws_size,
                              hipStream_t stream) {
  const float* lidar = (const float*)d_in[0];
  const float* image = (const float*)d_in[1];
  const float* cl_w = (const float*)d_in[2];
  const float* cl_b = (const float*)d_in[3];
  const float* bnl_g = (const float*)d_in[4];
  const float* bnl_b = (const float*)d_in[5];
  const float* bnl_m = (const float*)d_in[6];
  const float* bnl_v = (const float*)d_in[7];
  const float* ci_w = (const float*)d_in[8];
  const float* ci_b = (const float*)d_in[9];
  const float* bni_g = (const float*)d_in[10];
  const float* bni_b = (const float*)d_in[11];
  const float* bni_m = (const float*)d_in[12];
  const float* bni_v = (const float*)d_in[13];
  const float* qw = (const float*)d_in[14];
  const float* qb = (const float*)d_in[15];
  const float* kw = (const float*)d_in[16];
  const float* kb = (const float*)d_in[17];
  const float* vw = (const float*)d_in[18];
  const float* vb = (const float*)d_in[19];
  const float* ow = (const float*)d_in[20];
  const float* ob = (const float*)d_in[21];
  const float* ln1_g = (const float*)d_in[22];
  const float* ln1_b = (const float*)d_in[23];
  const float* w1 = (const float*)d_in[24];
  const float* b1 = (const float*)d_in[25];
  const float* w2 = (const float*)d_in[26];
  const float* b2 = (const float*)d_in[27];
  const float* ln2_g = (const float*)d_in[28];
  const float* ln2_b = (const float*)d_in[29];
  const float* op_w = (const float*)d_in[30];
  const float* op_b = (const float*)d_in[31];
  const float* sp_w = (const float*)d_in[32];
  const float* sp_b = (const float*)d_in[33];
  float* out = (float*)d_out;

  char* ws = (char*)d_ws;
  bf16* lidT = (bf16*)ws;
  bf16* imgT = (bf16*)(ws + 51380224);
  char* ov = ws + 51380224;
  bf16* Qb = (bf16*)(ov + 0);
  bf16* Kb = (bf16*)(ov + 3211264);
  bf16* Vt = (bf16*)(ov + 9633792);
  bf16* ctx = (bf16*)(ov + 12845056);
  bf16* x_b = (bf16*)(ov + 16056320);
  float* tmp1 = (float*)(ov + 19267584);
  float* x_f = (float*)(ov + 25690112);
  bf16* hmid = (bf16*)(ov + 32112640);
  float* oc2T = (float*)(ov + 38535168);
  size_t off = 102760448;
  auto carve = [&](size_t bytes) {
    void* p = ws + off;
    off += (bytes + 255) & ~(size_t)255;
    return p;
  };
  bf16* lseq_b = (bf16*)carve(3211264);
  bf16* iseq_b = (bf16*)carve(3211264);
  bf16* qwT = (bf16*)carve(131072);
  bf16* kwT = (bf16*)carve(131072);
  bf16* vwT = (bf16*)carve(131072);
  bf16* owT = (bf16*)carve(131072);
  bf16* w1t = (bf16*)carve(262144);
  bf16* w2t = (bf16*)carve(262144);
  bf16* clwT = (bf16*)carve(1179648);
  bf16* ciwT = (bf16*)carve(1179648);
  bf16* opwB = (bf16*)carve(131072);
  bf16* spwB = (bf16*)carve(131072);
  float* scale_l = (float*)carve(1024);
  float* shift_l = (float*)carve(1024);
  float* scale_i = (float*)carve(1024);
  float* shift_i = (float*)carve(1024);
  float* zp = (float*)carve(1024);
  float* tmp2 = tmp1;
  bf16* x2_pad = (bf16*)(void*)x_f;

  const float qscale = 0.17677669529663687f * 1.4426950408889634f;

  {  // t_in + all prep in one launch (independent work, range dispatch)
    PrepArgs a{cl_b, bnl_g, bnl_b, bnl_m, bnl_v,
               ci_b, bni_g, bni_b, bni_m, bni_v,
               scale_l, shift_l, scale_i, shift_i, zp,
               qw, kw, vw, ow, qwT, kwT, vwT, owT,
               w1, w2, w1t, w2t,
               op_w, sp_w, opwB, spwB,
               cl_w, ci_w, clwT, ciwT,
               lidar, image, lidT, imgT};
    tin_prep_k<<<3136 + 5250, 256, 0, stream>>>(a);
  }

  {  // fused conv (implicit im2col) + BN + ReLU
    ConvJob j0{lidT, clwT, scale_l, shift_l, lseq_b};
    ConvJob j1{imgT, ciwT, scale_i, shift_i, iseq_b};
    convgemm_k<<<dim3(98, 4, 2), 256, 0, stream>>>(j0, j1, (const bf16*)zp);
  }
  {  // Q (scaled), K projections (merged)
    GemmJobs3 js{};
    js.j[0] = {lseq_b, qwT, {nullptr, Qb, qb, nullptr, nullptr, 256, qscale}};
    js.j[1] = {iseq_b, kwT, {nullptr, Kb, kb, nullptr, nullptr, 256, 1.f}};
    gemm_bt<EPI_QKV, 64, 64><<<dim3(98, 4, 2), 256, 0, stream>>>(js, 256);
  }
  {  // V projection writing Vt directly (fused transpose)
    GemmJobs3 js{};
    js.j[0] = {iseq_b, vwT, {nullptr, Vt, vb, nullptr, nullptr, 3136, 1.f}};
    gemm_bt<EPI_QKV_VT, 64, 64><<<dim3(98, 4, 1), 256, 0, stream>>>(js, 256);
  }
  flash_k<<<dim3(784), 256, 0, stream>>>(Qb, Kb, Vt, ctx);
  {  // O projection + residual(lseq_b)
    GemmJobs3 js{};
    js.j[0] = {ctx, owT, {tmp1, nullptr, ob, nullptr, lseq_b, 256, 1.f}};
    gemm_bt<EPI_BIAS_ADDB, 64, 64><<<dim3(98, 4, 1), 256, 0, stream>>>(js, 256);
  }
  ln_k<<<1568, 256, 0, stream>>>(tmp1, ln1_g, ln1_b, nullptr, x_b);
  {  // FFN1
    GemmJobs3 js{};
    js.j[0] = {x_b, w1t, {nullptr, hmid, b1, nullptr, nullptr, 512, 1.f}};
    gemm_bt<EPI_BIAS_RELU_BF16, 64, 64><<<dim3(98, 8, 1), 256, 0, stream>>>(js, 256);
  }
  {  // FFN2 + residual(x_b, bf16)
    GemmJobs3 js{};
    js.j[0] = {hmid, w2t, {tmp2, nullptr, b2, nullptr, x_b, 256, 1.f}};
    gemm_bt<EPI_BIAS_ADDB, 64, 64><<<dim3(98, 4, 1), 256, 0, stream>>>(js, 512);
  }
  ln_k<<<1568, 256, 0, stream>>>(tmp2, ln2_g, ln2_b, nullptr, x2_pad);
  {  // op 1x1 conv -> channel-major oc2T [256][3136]
    GemmJobs3 js{};
    js.j[0] = {opwB, x2_pad, {oc2T, nullptr, op_b, nullptr, nullptr, 3136, 1.f}};
    js.j[1] = {opwB, x2_pad + (long)3136 * 256,
               {oc2T + (long)256 * 3136, nullptr, op_b, nullptr, nullptr, 3136, 1.f}};
    gemm_bt<EPI_ROWB_F32, 64, 64><<<dim3(4, 49, 2), 256, 0, stream>>>(js, 256);
  }
  {  // final: sp 1x1 conv + fused bilerp upsample-add, 128x128 tiles
    GemmJobs3 js{};
    js.j[0] = {spwB, lidT, {out, nullptr, sp_b, oc2T, nullptr, 50176, 1.f}};
    js.j[1] = {spwB, lidT + (long)50176 * 256,
               {out + (long)256 * 50176, nullptr, sp_b,
                oc2T + (long)256 * 3136, nullptr, 50176, 1.f}};
    gemm_bt<EPI_FINAL2, 128, 128><<<dim3(2, 392, 2), 256, 0, stream>>>(js, 256);
  }
}

// Round 16
// 291.687 us; speedup vs baseline: 1.0616x; 1.0616x over previous
//
#include <hip/hip_runtime.h>
#include <hip/hip_bf16.h>

typedef __bf16 bf16;
typedef __attribute__((ext_vector_type(8))) __bf16 bf16x8;
typedef __attribute__((ext_vector_type(4))) __bf16 bf16x4;
typedef __attribute__((ext_vector_type(4))) float f32x4;
typedef __attribute__((ext_vector_type(4))) unsigned int u32x4;

#define LN_EPS 1e-5f

__device__ __forceinline__ void gload16(const void* g, void* l) {
  __builtin_amdgcn_global_load_lds(
      (__attribute__((address_space(1))) void*)g,
      (__attribute__((address_space(3))) void*)l, 16, 0, 0);
}

__device__ __forceinline__ unsigned pk2(float a, float b) {
  unsigned ua = __builtin_bit_cast(unsigned short, (bf16)a);
  unsigned ub = __builtin_bit_cast(unsigned short, (bf16)b);
  return ua | (ub << 16);
}

__device__ __forceinline__ float fexp2(float x) {
  float r;
  asm("v_exp_f32 %0, %1" : "=v"(r) : "v"(x));
  return r;
}

// ---------------- t_in + all prep merged into ONE launch ----------------
struct PrepArgs {
  const float *cl_b, *bnl_g, *bnl_b, *bnl_m, *bnl_v;
  const float *ci_b, *bni_g, *bni_b, *bni_m, *bni_v;
  float *scale_l, *shift_l, *scale_i, *shift_i, *zp;
  const float *qw, *kw, *vw, *ow;
  bf16 *qwT, *kwT, *vwT, *owT;
  const float *w1, *w2;
  bf16 *w1t, *w2t;
  const float *op_w, *sp_w;
  bf16 *opwB, *spwB;
  const float *cl_w, *ci_w;
  bf16 *clwT, *ciwT;
  const float *lid, *img;
  bf16 *lidT, *imgT;
};

__global__ __launch_bounds__(256) void tin_prep_k(PrepArgs a) {
  __shared__ unsigned smem[128 * 68];
  const int bid0 = blockIdx.x;
  const int t = threadIdx.x;
  if (bid0 < 3136) {  // ---- t_in v5 ----
    int z = bid0 & 3;
    int rest = bid0 >> 2;
    int b = z & 1;
    const float* in = (z < 2) ? a.lid : a.img;
    bf16* out = (z < 2) ? a.lidT : a.imgT;
    int c0 = (rest & 1) * 128;
    long p0 = (long)(rest >> 1) * 128;
    const float* ib = in + (long)b * 256 * 50176;
    bf16* ob = out + (long)b * 50176 * 256;
    int q = t & 31;
    int cp = t >> 5;
#pragma unroll
    for (int pp = 0; pp < 8; ++pp) {
      int chl = pp * 16 + cp * 2;
      const float* s = ib + (long)(c0 + chl) * 50176 + p0 + q * 4;
      float4 av = *(const float4*)s;
      float4 bv = *(const float4*)(s + 50176);
      unsigned wv[4] = {pk2(av.x, bv.x), pk2(av.y, bv.y), pk2(av.z, bv.z),
                        pk2(av.w, bv.w)};
      int c = pp * 8 + cp;
#pragma unroll
      for (int j = 0; j < 4; ++j)
        smem[(q * 4 + j) * 68 + c] = wv[j];
    }
    __syncthreads();
    int c8 = t & 15;
#pragma unroll
    for (int pp = 0; pp < 8; ++pp) {
      int p = pp * 16 + (t >> 4);
      u32x4 vv = *(const u32x4*)&smem[p * 68 + c8 * 4];
      *(u32x4*)(ob + (p0 + p) * 256 + c0 + c8 * 8) = vv;
    }
    return;
  }
  const int bid = bid0 - 3136;
  float(*tile)[33] = (float(*)[33])smem;
  if (bid < 2) {
    bool z = bid != 0;
    const float* cb = z ? a.ci_b : a.cl_b;
    const float* g = z ? a.bni_g : a.bnl_g;
    const float* bb = z ? a.bni_b : a.bnl_b;
    const float* m = z ? a.bni_m : a.bnl_m;
    const float* v = z ? a.bni_v : a.bnl_v;
    float* sc = z ? a.scale_i : a.scale_l;
    float* sh = z ? a.shift_i : a.shift_l;
    float s = g[t] * rsqrtf(v[t] + LN_EPS);
    sc[t] = s;
    sh[t] = (cb[t] - m[t]) * s + bb[t];
    if (bid == 0) a.zp[t] = 0.f;
  } else if (bid < 514) {
    const float* in;
    bf16* out;
    int c0, r0, R, Cc;
    if (bid < 258) {
      int idx = bid - 2;
      int z = idx >> 6, rem = idx & 63;
      in = z == 0 ? a.qw : z == 1 ? a.kw : z == 2 ? a.vw : a.ow;
      out = z == 0 ? a.qwT : z == 1 ? a.kwT : z == 2 ? a.vwT : a.owT;
      c0 = (rem & 7) * 32;
      r0 = (rem >> 3) * 32;
      R = 256; Cc = 256;
    } else if (bid < 386) {
      int idx = bid - 258;
      in = a.w1; out = a.w1t;
      c0 = (idx & 15) * 32;
      r0 = (idx >> 4) * 32;
      R = 256; Cc = 512;
    } else {
      int idx = bid - 386;
      in = a.w2; out = a.w2t;
      c0 = (idx & 7) * 32;
      r0 = (idx >> 3) * 32;
      R = 512; Cc = 256;
    }
    int tx = t & 31, ty = t >> 5;
    for (int yy = ty; yy < 32; yy += 8)
      tile[yy][tx] = in[(long)(r0 + yy) * Cc + c0 + tx];
    __syncthreads();
    for (int yy = ty; yy < 32; yy += 8)
      out[(long)(c0 + yy) * R + r0 + tx] = (bf16)tile[tx][yy];
  } else if (bid < 642) {
    int idx = bid - 514;
    int bx = idx & 63;
    const float* in = (idx >> 6) ? a.sp_w : a.op_w;
    bf16* out = (idx >> 6) ? a.spwB : a.opwB;
    int i = (bx * 256 + t) * 4;
    float4 v = *(const float4*)(in + i);
    bf16x4 o = {(bf16)v.x, (bf16)v.y, (bf16)v.z, (bf16)v.w};
    *(bf16x4*)(out + i) = o;
  } else {
    int idx = bid - 642;
    int bx = idx % 2304;
    const float* w = (idx / 2304) ? a.ci_w : a.cl_w;
    bf16* o = (idx / 2304) ? a.ciwT : a.clwT;
    int gi = bx * 256 + t;
    int co = gi / 2304, r = gi - co * 2304;
    int k9 = r >> 8, ci = r & 255;
    o[gi] = (bf16)w[(co * 256 + ci) * 9 + k9];
  }
}

__global__ void ln_k(const float* __restrict__ in, const float* __restrict__ g,
                     const float* __restrict__ bb, float* __restrict__ outf,
                     bf16* __restrict__ outb) {
  int w = threadIdx.x >> 6, l = threadIdx.x & 63;
  long row = (long)blockIdx.x * 4 + w;
  float4 v = *(const float4*)(in + row * 256 + l * 4);
  float s = v.x + v.y + v.z + v.w;
  for (int m = 1; m < 64; m <<= 1) s += __shfl_xor(s, m);
  float mu = s * (1.0f / 256.0f);
  float dx = v.x - mu, dy = v.y - mu, dz = v.z - mu, dw = v.w - mu;
  float q = dx * dx + dy * dy + dz * dz + dw * dw;
  for (int m = 1; m < 64; m <<= 1) q += __shfl_xor(q, m);
  float rstd = rsqrtf(q * (1.0f / 256.0f) + LN_EPS);
  int c = l * 4;
  float y0 = dx * rstd * g[c] + bb[c];
  float y1 = dy * rstd * g[c + 1] + bb[c + 1];
  float y2 = dz * rstd * g[c + 2] + bb[c + 2];
  float y3 = dw * rstd * g[c + 3] + bb[c + 3];
  if (outf) {
    float4 o = {y0, y1, y2, y3};
    *(float4*)(outf + row * 256 + c) = o;
  }
  bf16x4 ob = {(bf16)y0, (bf16)y1, (bf16)y2, (bf16)y3};
  *(bf16x4*)(outb + row * 256 + c) = ob;
}

// ---------------- conv GEMM with implicit im2col (NHWC input) ----------------
struct ConvJob {
  const bf16* inT;
  const bf16* wT;
  const float* scale;
  const float* shift;
  bf16* out;
};

__global__ __launch_bounds__(256) void convgemm_k(ConvJob j0, ConvJob j1,
                                                  const bf16* zp) {
  const ConvJob jb = blockIdx.z ? j1 : j0;
  __shared__ bf16 lA[64 * 64];
  __shared__ bf16 lB[64 * 64];
  const int tid = threadIdx.x;
  const int w = tid >> 6, l = tid & 63;
  const int l15 = l & 15;
  const int m0 = blockIdx.x * 64;
  const int n0 = blockIdx.y * 64;
  const int mw = (w >> 1) * 32, nw = (w & 1) * 32;
  f32x4 acc[2][2] = {};
  const int srow = w * 8 + (l >> 3);
  const int kc8 = (l & 7) * 8;
  long rb[2];
  int voy[2], vox[2];
#pragma unroll
  for (int p = 0; p < 2; ++p) {
    int m = m0 + srow + p * 32;
    int b = m / 3136;
    int mm = m - b * 3136;
    int oy = mm / 56, ox = mm - oy * 56;
    rb[p] = ((long)b * 50176 + (long)(4 * oy - 1) * 224 + (4 * ox - 1)) * 256 + kc8;
    voy[p] = oy;
    vox[p] = ox;
  }
  const bf16* Bb = jb.wT + (long)(n0 + srow) * 2304 + kc8;
  bf16* lAp = &lA[srow * 64 + kc8];
  bf16* lBp = &lB[srow * 64 + kc8];
  const bf16* zsrc = zp + kc8;
#pragma unroll
  for (int st = 0; st < 36; ++st) {
    const int k9 = st >> 2, ci0 = (st & 3) * 64;
    const int ky = k9 / 3, kx = k9 - 3 * ky;
    const long koff = (long)(ky * 224 + kx) * 256 + ci0;
#pragma unroll
    for (int p = 0; p < 2; ++p) {
      bool ok = (voy[p] > 0 || ky > 0) && (vox[p] > 0 || kx > 0);
      const bf16* src = ok ? jb.inT + rb[p] + koff : zsrc;
      gload16(src, lAp + p * 32 * 64);
    }
    gload16(Bb + st * 64, lBp);
    gload16(Bb + 32 * 2304 + st * 64, lBp + 32 * 64);
    __syncthreads();
    const int kq = (l >> 4) * 8;
#pragma unroll
    for (int kk = 0; kk < 64; kk += 32) {
      bf16x8 af[2], bfv[2];
#pragma unroll
      for (int i = 0; i < 2; ++i)
        af[i] = *(const bf16x8*)&lA[(mw + i * 16 + l15) * 64 + kk + kq];
#pragma unroll
      for (int j = 0; j < 2; ++j)
        bfv[j] = *(const bf16x8*)&lB[(nw + j * 16 + l15) * 64 + kk + kq];
#pragma unroll
      for (int i = 0; i < 2; ++i)
#pragma unroll
        for (int j = 0; j < 2; ++j)
          acc[i][j] = __builtin_amdgcn_mfma_f32_16x16x32_bf16(af[i], bfv[j],
                                                              acc[i][j], 0, 0, 0);
    }
    __syncthreads();
  }
#pragma unroll
  for (int i = 0; i < 2; ++i)
#pragma unroll
    for (int j = 0; j < 2; ++j)
#pragma unroll
      for (int r = 0; r < 4; ++r) {
        const long row = m0 + mw + i * 16 + (l >> 4) * 4 + r;
        const long col = n0 + nw + j * 16 + l15;
        float v = fmaxf(acc[i][j][r] * jb.scale[col] + jb.shift[col], 0.f);
        jb.out[row * 256 + col] = (bf16)v;
      }
}

// ---------------- generic GEMM (templated BM/BN) ----------------

struct EpiParams {
  float* out0;
  bf16* out1;
  const float* v0;
  const float* res;
  const bf16* resb;
  int ldc;
  float mul;
};

struct GemmJob {
  const bf16* A;
  const bf16* Bt;
  EpiParams ep;
};

struct GemmJobs3 {
  GemmJob j[3];
};

enum { EPI_QKV = 0, EPI_BIAS_RELU_BF16 = 1, EPI_BIAS_ADD = 2,
       EPI_BIAS_ADDB = 3, EPI_ROWB_F32 = 4, EPI_FINAL2 = 5, EPI_QKV_VT = 6 };

template <int EPI, int BM, int BN>
__global__ __launch_bounds__(256) void gemm_bt(GemmJobs3 jobs, int K) {
  const GemmJob jb = jobs.j[blockIdx.z];
  const bf16* __restrict__ A = jb.A;
  const bf16* __restrict__ Bt = jb.Bt;
  const EpiParams ep = jb.ep;
  constexpr int MI = (BM == 128 && BN == 128) ? 4 : 2;
  constexpr int NJ = (BN == 128) ? 4 : 2;
  __shared__ bf16 lA[BM * 64];
  __shared__ bf16 lB[BN * 64];
  const int tid = threadIdx.x;
  const int w = tid >> 6, l = tid & 63;
  const int l15 = l & 15;
  const long m0 = (long)blockIdx.x * BM;
  const long n0 = (long)blockIdx.y * BN;
  const int mw = (BM == 128) ? ((BN == 128) ? (w >> 1) * 64 : w * 32)
                             : (w >> 1) * 32;
  const int nw = (BN == 128) ? (w & 1) * 64 : ((BM == 128) ? 0 : (w & 1) * 32);
  f32x4 acc[MI][NJ] = {};
  const int srow = w * 8 + (l >> 3);
  const int kc8 = (l & 7) * 8;
  const bf16* Ab = A + (m0 + srow) * (long)K + kc8;
  const bf16* Bb = Bt + (n0 + srow) * (long)K + kc8;
  bf16* lAp = &lA[srow * 64 + kc8];
  bf16* lBp = &lB[srow * 64 + kc8];
  for (int k0 = 0; k0 < K; k0 += 64) {
#pragma unroll
    for (int p = 0; p < BM / 32; ++p)
      gload16(Ab + (long)p * 32 * K + k0, lAp + p * 32 * 64);
#pragma unroll
    for (int p = 0; p < BN / 32; ++p)
      gload16(Bb + (long)p * 32 * K + k0, lBp + p * 32 * 64);
    __syncthreads();
    const int kq = (l >> 4) * 8;
#pragma unroll
    for (int kk = 0; kk < 64; kk += 32) {
      bf16x8 af[MI], bfv[NJ];
#pragma unroll
      for (int i = 0; i < MI; ++i)
        af[i] = *(const bf16x8*)&lA[(mw + i * 16 + l15) * 64 + kk + kq];
#pragma unroll
      for (int j = 0; j < NJ; ++j)
        bfv[j] = *(const bf16x8*)&lB[(nw + j * 16 + l15) * 64 + kk + kq];
#pragma unroll
      for (int i = 0; i < MI; ++i)
#pragma unroll
        for (int j = 0; j < NJ; ++j)
          acc[i][j] = __builtin_amdgcn_mfma_f32_16x16x32_bf16(af[i], bfv[j],
                                                              acc[i][j], 0, 0, 0);
    }
    __syncthreads();
  }
  const int ldc = ep.ldc;
#pragma unroll
  for (int i = 0; i < MI; ++i)
#pragma unroll
    for (int j = 0; j < NJ; ++j) {
      if constexpr (EPI == EPI_QKV_VT) {
        const long row0 = m0 + mw + i * 16 + (l >> 4) * 4;
        const int b = (int)(row0 / 3136);
        const int n = (int)(row0 - (long)b * 3136);
        const long col = n0 + nw + j * 16 + l15;
        bf16x4 ov;
#pragma unroll
        for (int r = 0; r < 4; ++r)
          ov[r] = (bf16)(acc[i][j][r] + ep.v0[col]);
        *(bf16x4*)(ep.out1 + ((long)b * 256 + col) * 3136 + n) = ov;
      } else if constexpr (EPI == EPI_FINAL2) {
        const long col = n0 + nw + j * 16 + l15;
        int colp = (int)col;
        int y = colp / 224, x = colp - y * 224;
        int ry = y & 3, rx = x & 3;
        int y0 = (y >> 2) - 1 + (ry >> 1);
        int x0 = (x >> 2) - 1 + (rx >> 1);
        float wy = (ry == 0) ? 0.625f : (ry == 1) ? 0.875f : (ry == 2) ? 0.125f : 0.375f;
        float wx = (rx == 0) ? 0.625f : (rx == 1) ? 0.875f : (rx == 2) ? 0.125f : 0.375f;
        int y0c = y0 > 0 ? y0 : 0, y1c = (y0 + 1) < 55 ? (y0 + 1) : 55;
        int x0c = x0 > 0 ? x0 : 0, x1c = (x0 + 1) < 55 ? (x0 + 1) : 55;
        const int o00 = y0c * 56 + x0c, o01 = y0c * 56 + x1c;
        const int o10 = y1c * 56 + x0c, o11 = y1c * 56 + x1c;
        const float w11 = wy * wx, w10 = wy * (1.f - wx);
        const float w01 = (1.f - wy) * wx, w00 = (1.f - wy) * (1.f - wx);
#pragma unroll
        for (int r = 0; r < 4; ++r) {
          const long row = m0 + mw + i * 16 + (l >> 4) * 4 + r;
          const float* ocr = ep.res + row * 3136;
          float up = w00 * ocr[o00] + w01 * ocr[o01] + w10 * ocr[o10] +
                     w11 * ocr[o11];
          ep.out0[row * ldc + col] = acc[i][j][r] + ep.v0[row] + up;
        }
      } else {
#pragma unroll
        for (int r = 0; r < 4; ++r) {
          const long row = m0 + mw + i * 16 + (l >> 4) * 4 + r;
          const long col = n0 + nw + j * 16 + l15;
          float v = acc[i][j][r];
          if constexpr (EPI == EPI_QKV) {
            ep.out1[row * ldc + col] = (bf16)((v + ep.v0[col]) * ep.mul);
          } else if constexpr (EPI == EPI_BIAS_RELU_BF16) {
            ep.out1[row * ldc + col] = (bf16)fmaxf(v + ep.v0[col], 0.f);
          } else if constexpr (EPI == EPI_BIAS_ADD) {
            ep.out0[row * ldc + col] = v + ep.v0[col] + ep.res[row * ldc + col];
          } else if constexpr (EPI == EPI_BIAS_ADDB) {
            ep.out0[row * ldc + col] =
                v + ep.v0[col] + (float)ep.resb[row * ldc + col];
          } else if constexpr (EPI == EPI_ROWB_F32) {
            ep.out0[row * ldc + col] = v + ep.v0[row];
          }
        }
      }
    }
}

// ---------------- flash attention v5 (unchanged) ----------------
__global__ __launch_bounds__(256) void flash_k(const bf16* __restrict__ Qg,
                                               const bf16* __restrict__ Kg,
                                               const bf16* __restrict__ Vt,
                                               bf16* __restrict__ ctx) {
  const int w = threadIdx.x >> 6, l = threadIdx.x & 63;
  const int fid = blockIdx.x;
  const int grp = (fid & 7) * 2 + ((fid >> 3) / 49);
  const int qt = (fid >> 3) % 49;
  const int b = grp >> 3, h = grp & 7;
  const int N = 3136;
  const int l15 = l & 15, g = l >> 4;
  const int q0 = (qt * 4 + w) * 16;
  const int kperm = 8 * (l15 >> 2) + (l15 & 3);
  __shared__ bf16 lds[2][4][512];

  bf16x8 qf = *(const bf16x8*)(Qg + ((long)(b * N + q0 + l15)) * 256 + h * 32 + g * 8);
  const bf16* Kb_ = Kg + ((long)b * N) * 256 + h * 32;
  const bf16* Vb_ = Vt + ((long)(b * 256 + h * 32)) * 3136;
  const long kOffA = (long)kperm * 256 + g * 8;
  const long kOffB = (long)(kperm + 4) * 256 + g * 8;
  const long vOff0 = (long)l15 * 3136 + g * 8;
  const long vOff1 = (long)(16 + l15) * 3136 + g * 8;

  f32x4 o0 = {}, o1 = {};
  float ls = 0.f;

  auto stage = [&](int buf, int kt) {
    const bf16* kp = Kb_ + (long)kt * 32 * 256;
    const bf16* vp = Vb_ + kt * 32;
    if (w == 0)
      gload16(kp + kOffA, &lds[buf][0][l * 8]);
    else if (w == 1)
      gload16(kp + kOffB, &lds[buf][1][l * 8]);
    else if (w == 2)
      gload16(vp + vOff0, &lds[buf][2][l * 8]);
    else
      gload16(vp + vOff1, &lds[buf][3][l * 8]);
  };

  stage(0, 0);
  __syncthreads();
  int cur = 0;
  for (int kt = 0; kt < 98; ++kt) {
    if (kt < 97) stage(cur ^ 1, kt + 1);
    bf16x8 kf0 = *(const bf16x8*)&lds[cur][0][l * 8];
    bf16x8 kf1 = *(const bf16x8*)&lds[cur][1][l * 8];
    bf16x8 vf0 = *(const bf16x8*)&lds[cur][2][l * 8];
    bf16x8 vf1 = *(const bf16x8*)&lds[cur][3][l * 8];
    f32x4 z = {};
    f32x4 s0 = __builtin_amdgcn_mfma_f32_16x16x32_bf16(kf0, qf, z, 0, 0, 0);
    f32x4 s1 = __builtin_amdgcn_mfma_f32_16x16x32_bf16(kf1, qf, z, 0, 0, 0);
    float p0 = fexp2(s0[0]), p1 = fexp2(s0[1]), p2 = fexp2(s0[2]), p3 = fexp2(s0[3]);
    float p4 = fexp2(s1[0]), p5 = fexp2(s1[1]), p6 = fexp2(s1[2]), p7 = fexp2(s1[3]);
    ls += ((p0 + p1) + (p2 + p3)) + ((p4 + p5) + (p6 + p7));
    u32x4 fp;
    fp[0] = pk2(p0, p1);
    fp[1] = pk2(p2, p3);
    fp[2] = pk2(p4, p5);
    fp[3] = pk2(p6, p7);
    bf16x8 pf = __builtin_bit_cast(bf16x8, fp);
    o0 = __builtin_amdgcn_mfma_f32_16x16x32_bf16(vf0, pf, o0, 0, 0, 0);
    o1 = __builtin_amdgcn_mfma_f32_16x16x32_bf16(vf1, pf, o1, 0, 0, 0);
    __syncthreads();
    cur ^= 1;
  }
  ls += __shfl_xor(ls, 16);
  ls += __shfl_xor(ls, 32);
  float inv = 1.0f / ls;
  long base = ((long)(b * N + q0 + l15)) * 256 + h * 32;
  bf16x4 ov0 = {(bf16)(o0[0] * inv), (bf16)(o0[1] * inv),
                (bf16)(o0[2] * inv), (bf16)(o0[3] * inv)};
  bf16x4 ov1 = {(bf16)(o1[0] * inv), (bf16)(o1[1] * inv),
                (bf16)(o1[2] * inv), (bf16)(o1[3] * inv)};
  *(bf16x4*)(ctx + base + g * 4) = ov0;
  *(bf16x4*)(ctx + base + 16 + g * 4) = ov1;
}

// ---------------- launch ----------------

extern "C" void kernel_launch(void* const* d_in, const int* in_sizes, int n_in,
                              void* d_out, int out_size, void* d_ws, size_t ws_size,
                              hipStream_t stream) {
  const float* lidar = (const float*)d_in[0];
  const float* image = (const float*)d_in[1];
  const float* cl_w = (const float*)d_in[2];
  const float* cl_b = (const float*)d_in[3];
  const float* bnl_g = (const float*)d_in[4];
  const float* bnl_b = (const float*)d_in[5];
  const float* bnl_m = (const float*)d_in[6];
  const float* bnl_v = (const float*)d_in[7];
  const float* ci_w = (const float*)d_in[8];
  const float* ci_b = (const float*)d_in[9];
  const float* bni_g = (const float*)d_in[10];
  const float* bni_b = (const float*)d_in[11];
  const float* bni_m = (const float*)d_in[12];
  const float* bni_v = (const float*)d_in[13];
  const float* qw = (const float*)d_in[14];
  const float* qb = (const float*)d_in[15];
  const float* kw = (const float*)d_in[16];
  const float* kb = (const float*)d_in[17];
  const float* vw = (const float*)d_in[18];
  const float* vb = (const float*)d_in[19];
  const float* ow = (const float*)d_in[20];
  const float* ob = (const float*)d_in[21];
  const float* ln1_g = (const float*)d_in[22];
  const float* ln1_b = (const float*)d_in[23];
  const float* w1 = (const float*)d_in[24];
  const float* b1 = (const float*)d_in[25];
  const float* w2 = (const float*)d_in[26];
  const float* b2 = (const float*)d_in[27];
  const float* ln2_g = (const float*)d_in[28];
  const float* ln2_b = (const float*)d_in[29];
  const float* op_w = (const float*)d_in[30];
  const float* op_b = (const float*)d_in[31];
  const float* sp_w = (const float*)d_in[32];
  const float* sp_b = (const float*)d_in[33];
  float* out = (float*)d_out;

  char* ws = (char*)d_ws;
  bf16* lidT = (bf16*)ws;
  bf16* imgT = (bf16*)(ws + 51380224);
  char* ov = ws + 51380224;
  bf16* Qb = (bf16*)(ov + 0);
  bf16* Kb = (bf16*)(ov + 3211264);
  bf16* Vt = (bf16*)(ov + 9633792);
  bf16* ctx = (bf16*)(ov + 12845056);
  bf16* x_b = (bf16*)(ov + 16056320);
  float* tmp1 = (float*)(ov + 19267584);
  float* x_f = (float*)(ov + 25690112);
  bf16* hmid = (bf16*)(ov + 32112640);
  float* oc2T = (float*)(ov + 38535168);
  size_t off = 102760448;
  auto carve = [&](size_t bytes) {
    void* p = ws + off;
    off += (bytes + 255) & ~(size_t)255;
    return p;
  };
  bf16* lseq_b = (bf16*)carve(3211264);
  bf16* iseq_b = (bf16*)carve(3211264);
  bf16* qwT = (bf16*)carve(131072);
  bf16* kwT = (bf16*)carve(131072);
  bf16* vwT = (bf16*)carve(131072);
  bf16* owT = (bf16*)carve(131072);
  bf16* w1t = (bf16*)carve(262144);
  bf16* w2t = (bf16*)carve(262144);
  bf16* clwT = (bf16*)carve(1179648);
  bf16* ciwT = (bf16*)carve(1179648);
  bf16* opwB = (bf16*)carve(131072);
  bf16* spwB = (bf16*)carve(131072);
  float* scale_l = (float*)carve(1024);
  float* shift_l = (float*)carve(1024);
  float* scale_i = (float*)carve(1024);
  float* shift_i = (float*)carve(1024);
  float* zp = (float*)carve(1024);
  float* tmp2 = tmp1;
  bf16* x2_pad = (bf16*)(void*)x_f;

  const float qscale = 0.17677669529663687f * 1.4426950408889634f;

  {  // t_in + all prep in one launch
    PrepArgs a{cl_b, bnl_g, bnl_b, bnl_m, bnl_v,
               ci_b, bni_g, bni_b, bni_m, bni_v,
               scale_l, shift_l, scale_i, shift_i, zp,
               qw, kw, vw, ow, qwT, kwT, vwT, owT,
               w1, w2, w1t, w2t,
               op_w, sp_w, opwB, spwB,
               cl_w, ci_w, clwT, ciwT,
               lidar, image, lidT, imgT};
    tin_prep_k<<<3136 + 5250, 256, 0, stream>>>(a);
  }

  {  // fused conv (implicit im2col) + BN + ReLU
    ConvJob j0{lidT, clwT, scale_l, shift_l, lseq_b};
    ConvJob j1{imgT, ciwT, scale_i, shift_i, iseq_b};
    convgemm_k<<<dim3(98, 4, 2), 256, 0, stream>>>(j0, j1, (const bf16*)zp);
  }
  {  // Q (scaled), K projections (merged)
    GemmJobs3 js{};
    js.j[0] = {lseq_b, qwT, {nullptr, Qb, qb, nullptr, nullptr, 256, qscale}};
    js.j[1] = {iseq_b, kwT, {nullptr, Kb, kb, nullptr, nullptr, 256, 1.f}};
    gemm_bt<EPI_QKV, 64, 64><<<dim3(98, 4, 2), 256, 0, stream>>>(js, 256);
  }
  {  // V projection writing Vt directly (fused transpose)
    GemmJobs3 js{};
    js.j[0] = {iseq_b, vwT, {nullptr, Vt, vb, nullptr, nullptr, 3136, 1.f}};
    gemm_bt<EPI_QKV_VT, 64, 64><<<dim3(98, 4, 1), 256, 0, stream>>>(js, 256);
  }
  flash_k<<<dim3(784), 256, 0, stream>>>(Qb, Kb, Vt, ctx);
  {  // O projection + residual(lseq_b)
    GemmJobs3 js{};
    js.j[0] = {ctx, owT, {tmp1, nullptr, ob, nullptr, lseq_b, 256, 1.f}};
    gemm_bt<EPI_BIAS_ADDB, 64, 64><<<dim3(98, 4, 1), 256, 0, stream>>>(js, 256);
  }
  ln_k<<<1568, 256, 0, stream>>>(tmp1, ln1_g, ln1_b, nullptr, x_b);
  {  // FFN1
    GemmJobs3 js{};
    js.j[0] = {x_b, w1t, {nullptr, hmid, b1, nullptr, nullptr, 512, 1.f}};
    gemm_bt<EPI_BIAS_RELU_BF16, 64, 64><<<dim3(98, 8, 1), 256, 0, stream>>>(js, 256);
  }
  {  // FFN2 + residual(x_b, bf16)
    GemmJobs3 js{};
    js.j[0] = {hmid, w2t, {tmp2, nullptr, b2, nullptr, x_b, 256, 1.f}};
    gemm_bt<EPI_BIAS_ADDB, 64, 64><<<dim3(98, 4, 1), 256, 0, stream>>>(js, 512);
  }
  ln_k<<<1568, 256, 0, stream>>>(tmp2, ln2_g, ln2_b, nullptr, x2_pad);
  {  // op 1x1 conv -> channel-major oc2T [256][3136]
    GemmJobs3 js{};
    js.j[0] = {opwB, x2_pad, {oc2T, nullptr, op_b, nullptr, nullptr, 3136, 1.f}};
    js.j[1] = {opwB, x2_pad + (long)3136 * 256,
               {oc2T + (long)256 * 3136, nullptr, op_b, nullptr, nullptr, 3136, 1.f}};
    gemm_bt<EPI_ROWB_F32, 64, 64><<<dim3(4, 49, 2), 256, 0, stream>>>(js, 256);
  }
  {  // final: sp 1x1 conv + fused bilerp upsample-add, 64x64 tiles
    GemmJobs3 js{};
    js.j[0] = {spwB, lidT, {out, nullptr, sp_b, oc2T, nullptr, 50176, 1.f}};
    js.j[1] = {spwB, lidT + (long)50176 * 256,
               {out + (long)256 * 50176, nullptr, sp_b,
                oc2T + (long)256 * 3136, nullptr, 50176, 1.f}};
    gemm_bt<EPI_FINAL2, 64, 64><<<dim3(4, 784, 2), 256, 0, stream>>>(js, 256);
  }
}